// Round 15
// baseline (22.665 us; speedup 1.0000x reference)
//
#include <hip/hip_runtime.h>

#define N_NODES   10000
#define C_DIM     128
#define H_DIM     8
#define YZ_TOTAL  (N_NODES * H_DIM)
#define YZ_BLOCKS ((N_NODES * 32) / 256)     /* 1250 */

// clang-native vector types
typedef _Float16 h2 __attribute__((ext_vector_type(2)));
typedef _Float16 h8 __attribute__((ext_vector_type(8)));
typedef float    fx4 __attribute__((ext_vector_type(4)));

// ---------------------------------------------------------------------------
// K1: yz tables only (copy phase moved into K2). 32 thr/node k-split butterfly.
// x is read-once => NT loads (no L2 allocation); W/b cached (4KB, hot).
// ---------------------------------------------------------------------------
__global__ void __launch_bounds__(256)
precompute_yz(const float* __restrict__ x, const float* __restrict__ W,
              const float* __restrict__ b, _Float16* __restrict__ yzh) {
    const int t = blockIdx.x * blockDim.x + threadIdx.x;
    const int n = t >> 5;
    if (n >= N_NODES) return;
    const int w  = t & 31;
    const int s  = w >> 2;
    const int hp = w & 3;
    const int h0 = hp * 2;

    const fx4* xr4 = (const fx4*)(x + (size_t)n * C_DIM) + s * 4;
    fx4 xv0 = __builtin_nontemporal_load(xr4 + 0);   // read-once: bypass L2
    fx4 xv1 = __builtin_nontemporal_load(xr4 + 1);
    fx4 xv2 = __builtin_nontemporal_load(xr4 + 2);
    fx4 xv3 = __builtin_nontemporal_load(xr4 + 3);
    const float xk[16] = { xv0.x,xv0.y,xv0.z,xv0.w, xv1.x,xv1.y,xv1.z,xv1.w,
                           xv2.x,xv2.y,xv2.z,xv2.w, xv3.x,xv3.y,xv3.z,xv3.w };

    const int k0 = s * 16;
    const float* wr = W + (size_t)k0 * H_DIM + h0;
    const float* wc = W + (size_t)(C_DIM + k0) * H_DIM + h0;

    float ar0 = 0.f, ar1 = 0.f, ac0 = 0.f, ac1 = 0.f;
#pragma unroll
    for (int j = 0; j < 16; ++j) {
        float2 wr2 = *(const float2*)(wr + j * H_DIM);
        float2 wc2 = *(const float2*)(wc + j * H_DIM);
        ar0 = fmaf(xk[j], wr2.x, ar0);
        ar1 = fmaf(xk[j], wr2.y, ar1);
        ac0 = fmaf(xk[j], wc2.x, ac0);
        ac1 = fmaf(xk[j], wc2.y, ac1);
    }
#pragma unroll
    for (int m = 4; m <= 16; m <<= 1) {
        ar0 += __shfl_xor(ar0, m, 64);
        ar1 += __shfl_xor(ar1, m, 64);
        ac0 += __shfl_xor(ac0, m, 64);
        ac1 += __shfl_xor(ac1, m, 64);
    }
    if (s == 0) {
        float2 bb = *(const float2*)(b + h0);
        h2 yv = { (_Float16)(ar0 + bb.x), (_Float16)(ar1 + bb.y) };
        h2 zv = { (_Float16)ac0,          (_Float16)ac1 };
        *(h2*)(yzh + (size_t)n * H_DIM + h0)            = yv;
        *(h2*)(yzh + YZ_TOTAL + (size_t)n * H_DIM + h0) = zv;
    }
}

// ---------------------------------------------------------------------------
// K2: gather + sigmoid + alpha + idx pass-through (ei read ONCE, serves both).
// Streams/outputs NT (no L2 alloc); yzh gathers cached (table stays resident).
// ---------------------------------------------------------------------------
__device__ __forceinline__ float sigmoid_fast(float v) {
    return __builtin_amdgcn_rcpf(1.f + __expf(-v));
}

__global__ void __launch_bounds__(256)
edge_alpha(const int* __restrict__ ei, const float* __restrict__ ea,
           const _Float16* __restrict__ yzh, float* __restrict__ out, int E) {
    const int e = blockIdx.x * blockDim.x + threadIdx.x;
    if (e >= E) return;
    const size_t ib = (size_t)E * H_DIM;

    int   r = __builtin_nontemporal_load(ei + e);        // stream: no L2 alloc
    int   c = __builtin_nontemporal_load(ei + E + e);
    float a = __builtin_nontemporal_load(ea + e);

    h8 yv = *(const h8*)(yzh + (size_t)r * H_DIM);       // cached gather
    h8 zv = *(const h8*)(yzh + YZ_TOTAL + (size_t)c * H_DIM);

    // idx pass-through (r,c already in registers — ei not re-read)
    __builtin_nontemporal_store((float)r, out + ib + e);
    __builtin_nontemporal_store((float)c, out + ib + E + e);

    const bool self = (r == c);
    float res[8];
#pragma unroll
    for (int h = 0; h < 8; ++h) {
        float v = (float)yv[h] + (float)zv[h];
        res[h] = self ? 1.f : sigmoid_fast(v) * a;
    }

    fx4 lo = { res[0], res[1], res[2], res[3] };
    fx4 hi = { res[4], res[5], res[6], res[7] };
    __builtin_nontemporal_store(lo, (fx4*)(out + (size_t)e * H_DIM));
    __builtin_nontemporal_store(hi, (fx4*)(out + (size_t)e * H_DIM + 4));
}

extern "C" void kernel_launch(void* const* d_in, const int* in_sizes, int n_in,
                              void* d_out, int out_size, void* d_ws, size_t ws_size,
                              hipStream_t stream) {
    const float* x  = (const float*)d_in[0];
    const int*   ei = (const int*)d_in[1];   // int32 on device per harness convention
    const float* ea = (const float*)d_in[2];
    const float* W  = (const float*)d_in[3];
    const float* b  = (const float*)d_in[4];
    float* out = (float*)d_out;
    _Float16* yzh = (_Float16*)d_ws;         // 2*N*H*2 = 320 KB
    const int E = in_sizes[2];               // 640000

    {
        hipLaunchKernelGGL(precompute_yz, dim3(YZ_BLOCKS), dim3(256), 0, stream,
                           x, W, b, yzh);
    }
    {
        const int grid = (E + 255) / 256;                        // 2500
        hipLaunchKernelGGL(edge_alpha, dim3(grid), dim3(256), 0, stream,
                           ei, ea, yzh, out, E);
    }
}

// Round 16
// 22.375 us; speedup vs baseline: 1.0130x; 1.0130x over previous
//
#include <hip/hip_runtime.h>

#define N_NODES   10000
#define C_DIM     128
#define H_DIM     8
#define YZ_TOTAL  (N_NODES * H_DIM)
#define YZ_BLOCKS ((N_NODES * 32) / 256)     /* 1250 */

// clang-native vector types
typedef _Float16 h2 __attribute__((ext_vector_type(2)));
typedef _Float16 h8 __attribute__((ext_vector_type(8)));
typedef float    fx4 __attribute__((ext_vector_type(4)));

// ---------------------------------------------------------------------------
// K1 (R14 config, measured 22.34us): yz tables (32 thr/node, k-split
// butterfly, f16-packed output) + NT idx pass-through in trailing blocks.
// ---------------------------------------------------------------------------
__global__ void __launch_bounds__(256)
k1_yz_and_index(const float* __restrict__ x, const float* __restrict__ W,
                const float* __restrict__ b, const int* __restrict__ ei,
                float* __restrict__ out, _Float16* __restrict__ yzh, int E) {
    const int bid = blockIdx.x;

    if (bid < YZ_BLOCKS) {
        const int t = bid * 256 + threadIdx.x;
        const int n = t >> 5;
        if (n >= N_NODES) return;
        const int w  = t & 31;
        const int s  = w >> 2;
        const int hp = w & 3;
        const int h0 = hp * 2;

        const float4* xr4 = (const float4*)(x + (size_t)n * C_DIM) + s * 4;
        float4 xv0 = xr4[0], xv1 = xr4[1], xv2 = xr4[2], xv3 = xr4[3];
        const float xk[16] = { xv0.x,xv0.y,xv0.z,xv0.w, xv1.x,xv1.y,xv1.z,xv1.w,
                               xv2.x,xv2.y,xv2.z,xv2.w, xv3.x,xv3.y,xv3.z,xv3.w };

        const int k0 = s * 16;
        const float* wr = W + (size_t)k0 * H_DIM + h0;
        const float* wc = W + (size_t)(C_DIM + k0) * H_DIM + h0;

        float ar0 = 0.f, ar1 = 0.f, ac0 = 0.f, ac1 = 0.f;
#pragma unroll
        for (int j = 0; j < 16; ++j) {
            float2 wr2 = *(const float2*)(wr + j * H_DIM);
            float2 wc2 = *(const float2*)(wc + j * H_DIM);
            ar0 = fmaf(xk[j], wr2.x, ar0);
            ar1 = fmaf(xk[j], wr2.y, ar1);
            ac0 = fmaf(xk[j], wc2.x, ac0);
            ac1 = fmaf(xk[j], wc2.y, ac1);
        }
#pragma unroll
        for (int m = 4; m <= 16; m <<= 1) {
            ar0 += __shfl_xor(ar0, m, 64);
            ar1 += __shfl_xor(ar1, m, 64);
            ac0 += __shfl_xor(ac0, m, 64);
            ac1 += __shfl_xor(ac1, m, 64);
        }
        if (s == 0) {
            float2 bb = *(const float2*)(b + h0);
            h2 yv = { (_Float16)(ar0 + bb.x), (_Float16)(ar1 + bb.y) };
            h2 zv = { (_Float16)ac0,          (_Float16)ac1 };
            *(h2*)(yzh + (size_t)n * H_DIM + h0)            = yv;
            *(h2*)(yzh + YZ_TOTAL + (size_t)n * H_DIM + h0) = zv;
        }
    } else {
        const size_t ib = (size_t)E * H_DIM;
        const int t = (bid - YZ_BLOCKS) * 256 + threadIdx.x;
        const int i = t * 4;
        const int total = 2 * E;
        if (i + 3 < total) {
            int4 v = *(const int4*)(ei + i);
            fx4 f = { (float)v.x, (float)v.y, (float)v.z, (float)v.w };
            __builtin_nontemporal_store(f, (fx4*)(out + ib + i));
        } else {
            for (int j = i; j < total; ++j) out[ib + j] = (float)ei[j];
        }
    }
}

// ---------------------------------------------------------------------------
// K2 (R14 config): 1 thread/edge; NT stream loads (ei/ea), cached yzh
// gathers (one dwordx4 each), rcp sigmoid, NT alpha stores.
// ---------------------------------------------------------------------------
__device__ __forceinline__ float sigmoid_fast(float v) {
    return __builtin_amdgcn_rcpf(1.f + __expf(-v));
}

__global__ void edge_alpha(const int* __restrict__ ei,
                           const float* __restrict__ ea,
                           const _Float16* __restrict__ yzh,
                           float* __restrict__ out, int E) {
    const int e = blockIdx.x * blockDim.x + threadIdx.x;
    if (e >= E) return;
    int   r = __builtin_nontemporal_load(ei + e);        // stream: no L2 alloc
    int   c = __builtin_nontemporal_load(ei + E + e);
    float a = __builtin_nontemporal_load(ea + e);

    h8 yv = *(const h8*)(yzh + (size_t)r * H_DIM);       // cached gather
    h8 zv = *(const h8*)(yzh + YZ_TOTAL + (size_t)c * H_DIM);

    const bool self = (r == c);
    float res[8];
#pragma unroll
    for (int h = 0; h < 8; ++h) {
        float v = (float)yv[h] + (float)zv[h];
        res[h] = self ? 1.f : sigmoid_fast(v) * a;
    }

    fx4 lo = { res[0], res[1], res[2], res[3] };
    fx4 hi = { res[4], res[5], res[6], res[7] };
    __builtin_nontemporal_store(lo, (fx4*)(out + (size_t)e * H_DIM));
    __builtin_nontemporal_store(hi, (fx4*)(out + (size_t)e * H_DIM + 4));
}

extern "C" void kernel_launch(void* const* d_in, const int* in_sizes, int n_in,
                              void* d_out, int out_size, void* d_ws, size_t ws_size,
                              hipStream_t stream) {
    const float* x  = (const float*)d_in[0];
    const int*   ei = (const int*)d_in[1];   // int32 on device per harness convention
    const float* ea = (const float*)d_in[2];
    const float* W  = (const float*)d_in[3];
    const float* b  = (const float*)d_in[4];
    float* out = (float*)d_out;
    _Float16* yzh = (_Float16*)d_ws;         // 2*N*H*2 = 320 KB
    const int E = in_sizes[2];               // 640000

    {
        const int conv_threads = (2 * E + 3) / 4;                // 320000
        const int conv_blocks  = (conv_threads + 255) / 256;     // 1250
        const int grid = YZ_BLOCKS + conv_blocks;                // 2500
        hipLaunchKernelGGL(k1_yz_and_index, dim3(grid), dim3(256), 0, stream,
                           x, W, b, ei, out, yzh, E);
    }
    {
        const int grid = (E + 255) / 256;                        // 2500
        hipLaunchKernelGGL(edge_alpha, dim3(grid), dim3(256), 0, stream,
                           ei, ea, yzh, out, E);
    }
}